// Round 6
// baseline (928.926 us; speedup 1.0000x reference)
//
#include <hip/hip_runtime.h>
#include <hip/hip_bf16.h>
#include <stdint.h>

// ---------------------------------------------------------------------------
// LSTM2 fused v2: 3 stacked single-step LSTM cells (h0=c0=0 => f-gate dead)
// + fc1 in ONE kernel. 128 M-rows/block, 512 threads (8 waves = 2 row x 4 col).
// h1/h2/h3 ping-pong in LDS (XOR-swizzled). W streams from L2 into registers
// with one-step double-buffered prefetch; NO barriers inside K-loops.
// fc2 is a tiny follow-up kernel. ALL I/O f32; internals bf16 MFMA.
// ---------------------------------------------------------------------------

typedef __attribute__((ext_vector_type(8))) short bf16x8;
typedef __attribute__((ext_vector_type(4))) float f32x4;

#define M_ROWS 172032
#define BATCH  8192

__device__ __forceinline__ float bf2f(unsigned short u) {
    union { unsigned int i; float f; } v; v.i = ((unsigned int)u) << 16; return v.f;
}
__device__ __forceinline__ unsigned short f2bf(float f) {
    union { float f; unsigned int i; } v; v.f = f;
    unsigned int r = v.i + 0x7fffu + ((v.i >> 16) & 1u);
    return (unsigned short)(r >> 16);
}
__device__ __forceinline__ float sigmoidf_(float x) {
    return __builtin_amdgcn_rcpf(1.0f + __expf(-x));   // inf-safe
}
__device__ __forceinline__ float tanhf_(float x) {
    x = fminf(fmaxf(x, -20.0f), 20.0f);
    float e = __expf(-2.0f * x);
    return (1.0f - e) * __builtin_amdgcn_rcpf(1.0f + e);
}
// async global->LDS DMA: 16B/lane, dest = wave-uniform base + lane*16
__device__ __forceinline__ void g2l16(const unsigned short* g, unsigned short* l) {
    __builtin_amdgcn_global_load_lds(
        (const __attribute__((address_space(1))) unsigned int*)g,
        (__attribute__((address_space(3))) unsigned int*)l, 16, 0, 0);
}

// ---------------------------------------------------------------------------
// f32 -> bf16 bulk convert (weights), n4 = n/4
// ---------------------------------------------------------------------------
__global__ __launch_bounds__(256) void k_convert(
    const float* __restrict__ src, unsigned short* __restrict__ dst, int n4)
{
    int i = blockIdx.x * 256 + threadIdx.x;
    if (i < n4) {
        float4 v = ((const float4*)src)[i];
        ushort4 o;
        o.x = f2bf(v.x); o.y = f2bf(v.y); o.z = f2bf(v.z); o.w = f2bf(v.w);
        ((ushort4*)dst)[i] = o;
    }
}

// ---------------------------------------------------------------------------
// x (Bc, 128, 21) f32 -> xt (Bc*21, 128) bf16 row-major. One block per b.
// ---------------------------------------------------------------------------
__global__ __launch_bounds__(256) void k_transpose(
    const float* __restrict__ x, unsigned short* __restrict__ xt)
{
    __shared__ unsigned short tile[128 * 22];
    const int b = blockIdx.x, tid = threadIdx.x;
    const float* xb = x + (size_t)b * 2688;
    for (int idx = tid; idx < 2688; idx += 256) {
        int i = idx / 21, t = idx - i * 21;
        tile[i * 22 + t] = f2bf(xb[idx]);
    }
    __syncthreads();
    unsigned short* xtb = xt + (size_t)b * 2688;
    for (int idx = tid; idx < 2688; idx += 256) {
        int t = idx >> 7, i = idx & 127;
        xtb[t * 128 + i] = tile[i * 22 + t];
    }
}

// ---------------------------------------------------------------------------
// One LSTM layer, 128 rows, entirely LDS->LDS.
// bufIn:  LDS [128][K] bf16, granule-swizzled (phys granule = g ^ (row&7))
// bufOut: LDS [128][HG] bf16, same swizzle
// W: global bf16 (4*HG, K) row-major, gates i,f,g,o (f skipped, c0=0).
// 8 waves: rw=wave>>2 (64 rows each), cw=wave&3 (32 cols per 128-col pass).
// W frags double-buffered in registers (prefetch next k-step).
// ---------------------------------------------------------------------------
template<int K, int HG>
__device__ __forceinline__ void lstm_layer(
    const unsigned short* bufIn, unsigned short* bufOut,
    const unsigned short* __restrict__ W,
    const float* __restrict__ bih, const float* __restrict__ bhh,
    int rw, int cw, int quad, int rsel)
{
    const int r7 = rsel & 7;
    constexpr int S = K / 32;

#pragma unroll
    for (int pass = 0; pass < HG / 128; ++pass) {
        const int cbase = pass * 128 + cw * 32;

        float bias[3][2];
        const unsigned short* wp[3][2];
#pragma unroll
        for (int g = 0; g < 3; ++g) {
            int gb = (g == 0) ? 0 : (g + 1) * HG;   // i->0, g->2HG, o->3HG
#pragma unroll
            for (int n = 0; n < 2; ++n) {
                int col = cbase + n * 16 + rsel;
                bias[g][n] = bih[gb + col] + bhh[gb + col];
                wp[g][n] = W + (size_t)(gb + col) * K + quad * 8;
            }
        }

        f32x4 acc[3][4][2];
#pragma unroll
        for (int g = 0; g < 3; ++g)
#pragma unroll
            for (int m = 0; m < 4; ++m)
#pragma unroll
                for (int n = 0; n < 2; ++n)
                    acc[g][m][n] = (f32x4){0.f, 0.f, 0.f, 0.f};

        bf16x8 bcur[3][2], bnxt[3][2];
#pragma unroll
        for (int g = 0; g < 3; ++g)
#pragma unroll
            for (int n = 0; n < 2; ++n)
                bcur[g][n] = *(const bf16x8*)(wp[g][n]);

#pragma unroll
        for (int s = 0; s < S; ++s) {
            bf16x8 af[4];
            const int gsw = ((s * 4 + quad) ^ r7) * 8;   // swizzled granule
#pragma unroll
            for (int m = 0; m < 4; ++m)
                af[m] = *(const bf16x8*)&bufIn[(rw * 64 + m * 16 + rsel) * K + gsw];
            if (s + 1 < S) {
#pragma unroll
                for (int g = 0; g < 3; ++g)
#pragma unroll
                    for (int n = 0; n < 2; ++n)
                        bnxt[g][n] = *(const bf16x8*)(wp[g][n] + (s + 1) * 32);
            }
#pragma unroll
            for (int g = 0; g < 3; ++g)
#pragma unroll
                for (int m = 0; m < 4; ++m)
#pragma unroll
                    for (int n = 0; n < 2; ++n)
                        acc[g][m][n] = __builtin_amdgcn_mfma_f32_16x16x32_bf16(
                            af[m], bcur[g][n], acc[g][m][n], 0, 0, 0);
#pragma unroll
            for (int g = 0; g < 3; ++g)
#pragma unroll
                for (int n = 0; n < 2; ++n)
                    bcur[g][n] = bnxt[g][n];
        }

        // epilogue: C/D layout col = lane&15 (=rsel), row = quad*4 + reg
#pragma unroll
        for (int m = 0; m < 4; ++m)
#pragma unroll
            for (int n = 0; n < 2; ++n) {
                f32x4 vi = acc[0][m][n], vg = acc[1][m][n], vo = acc[2][m][n];
                int col = cbase + n * 16 + rsel;
#pragma unroll
                for (int r = 0; r < 4; ++r) {
                    int row = rw * 64 + m * 16 + quad * 4 + r;
                    float cv = sigmoidf_(vi[r] + bias[0][n]) * tanhf_(vg[r] + bias[1][n]);
                    float h  = sigmoidf_(vo[r] + bias[2][n]) * tanhf_(cv);
                    bufOut[row * HG + (((col >> 3) ^ (row & 7)) * 8) + (col & 7)] = f2bf(h);
                }
            }
    }
}

// ---------------------------------------------------------------------------
// Fused L1+L2+L3+fc1. Block = 128 M-rows, 512 threads (8 waves).
// LDS: bufA (xt 128x128 -> h2 128x256) / bufB (h1 128x256 -> h3 128x128).
// ---------------------------------------------------------------------------
__global__ __launch_bounds__(512, 2) void k_fused(
    const unsigned short* __restrict__ xt,   // (R,128) bf16
    const unsigned short* __restrict__ W1,
    const unsigned short* __restrict__ W2,
    const unsigned short* __restrict__ W3,
    const float* __restrict__ b1i, const float* __restrict__ b1h,
    const float* __restrict__ b2i, const float* __restrict__ b2h,
    const float* __restrict__ b3i, const float* __restrict__ b3h,
    const float* __restrict__ fc1w, const float* __restrict__ fc1b,
    float* __restrict__ y)                   // (R,) f32
{
    __shared__ __align__(16) unsigned short bufA[128 * 256];
    __shared__ __align__(16) unsigned short bufB[128 * 256];
    __shared__ float ypart[4][128];

    const int tid  = threadIdx.x;
    const int wave = tid >> 6;
    const int lane = tid & 63;
    const int rw   = wave >> 2;   // 0..1: 64-row band
    const int cw   = wave & 3;    // 0..3: 32-col slice per pass
    const int quad = lane >> 4;
    const int rsel = lane & 15;
    const int r0   = blockIdx.x * 128;

    // ---- DMA xt block (128 rows x 128 k) into bufA, swizzled ----
    // DMA d covers rows d*4..d*4+3 (4 rows x 256B); lane l -> row d*4+(l>>4),
    // phys granule l&15; source granule = (l&15) ^ (row&7)  (self-inverse)
#pragma unroll
    for (int i = 0; i < 4; ++i) {
        int d   = wave * 4 + i;          // 0..31
        int row = d * 4 + (lane >> 4);
        int g   = (lane & 15) ^ (row & 7);
        g2l16(xt + (size_t)(r0 + row) * 128 + g * 8, &bufA[d * 512]);
    }
    __syncthreads();

    lstm_layer<128, 256>(bufA, bufB, W1, b1i, b1h, rw, cw, quad, rsel);
    __syncthreads();
    lstm_layer<256, 256>(bufB, bufA, W2, b2i, b2h, rw, cw, quad, rsel);
    __syncthreads();
    lstm_layer<256, 128>(bufA, bufB, W3, b3i, b3h, rw, cw, quad, rsel);
    __syncthreads();

    // ---- fc1: y[row] = fc1b + sum_c fc1w[c] * h3[row][c] ----
    {
        int row = tid & 127, part = tid >> 7;   // 4 parts x 32 cols
        float s = 0.f;
#pragma unroll 8
        for (int i = 0; i < 32; ++i) {
            int c = part * 32 + i;
            s += fc1w[c] * bf2f(bufB[row * 128 + (((c >> 3) ^ (row & 7)) * 8) + (c & 7)]);
        }
        ypart[part][row] = s;
        __syncthreads();
        if (tid < 128)
            y[r0 + tid] = fc1b[0] + ypart[0][tid] + ypart[1][tid]
                        + ypart[2][tid] + ypart[3][tid];
    }
}

// ---------------------------------------------------------------------------
// fc2: out[b,tp] = fc2b[tp] + sum_t y[b,t] * fc2w[tp,t].  8 b per block.
// ---------------------------------------------------------------------------
__global__ __launch_bounds__(256) void k_fc2(
    const float* __restrict__ y, const float* __restrict__ fc2w,
    const float* __restrict__ fc2b, float* __restrict__ out)
{
    __shared__ float yl[168], f2l[441], f2bl[21];
    const int tid = threadIdx.x;
    const int b0 = blockIdx.x * 8;
    for (int i = tid; i < 441; i += 256) f2l[i] = fc2w[i];
    if (tid < 21) f2bl[tid] = fc2b[tid];
    if (tid < 168) yl[tid] = y[(size_t)b0 * 21 + tid];
    __syncthreads();
    if (tid < 168) {
        int bloc = tid / 21, tp = tid - bloc * 21;
        float s = f2bl[tp];
#pragma unroll
        for (int t = 0; t < 21; ++t)
            s += yl[bloc * 21 + t] * f2l[tp * 21 + t];
        out[(size_t)(b0 + bloc) * 21 + tp] = s;
    }
}

// ---------------------------------------------------------------------------
extern "C" void kernel_launch(void* const* d_in, const int* in_sizes, int n_in,
                              void* d_out, int out_size, void* d_ws, size_t ws_size,
                              hipStream_t stream)
{
    const float* x    = (const float*)d_in[0];
    const float* W1   = (const float*)d_in[1];
    const float* b1i  = (const float*)d_in[2];
    const float* b1h  = (const float*)d_in[3];
    const float* W2   = (const float*)d_in[4];
    const float* b2i  = (const float*)d_in[5];
    const float* b2h  = (const float*)d_in[6];
    const float* W3   = (const float*)d_in[7];
    const float* b3i  = (const float*)d_in[8];
    const float* b3h  = (const float*)d_in[9];
    const float* fc1w = (const float*)d_in[10];
    const float* fc1b = (const float*)d_in[11];
    const float* fc2w = (const float*)d_in[12];
    const float* fc2b = (const float*)d_in[13];
    float* out = (float*)d_out;

    // ws: [Wc1 1024x128][Wc2 1024x256][Wc3 512x256] bf16 (1 MB),
    // then per-chunk: xt (R x 128 bf16) + y (R f32) = 260 B/row.
    unsigned short* Wc1 = (unsigned short*)d_ws;
    unsigned short* Wc2 = Wc1 + 131072;
    unsigned short* Wc3 = Wc2 + 262144;
    unsigned short* buf = Wc3 + 131072;          // 1 MB in

    int C = 1;
    while (C < 64 && 1048576 + (size_t)(M_ROWS / C) * 260 > ws_size) C <<= 1;
    const int R  = M_ROWS / C;   // multiple of 2688 (= 21*128), so R/128 integral
    const int Bc = BATCH / C;

    unsigned short* xt = buf;
    float* y = (float*)(xt + (size_t)R * 128);

    k_convert<<<128, 256, 0, stream>>>(W1, Wc1, 32768);
    k_convert<<<256, 256, 0, stream>>>(W2, Wc2, 65536);
    k_convert<<<128, 256, 0, stream>>>(W3, Wc3, 32768);

    for (int c = 0; c < C; ++c) {
        const float* xc = x + (size_t)c * Bc * 2688;
        k_transpose<<<Bc, 256, 0, stream>>>(xc, xt);
        k_fused<<<R / 128, 512, 0, stream>>>(xt, Wc1, Wc2, Wc3,
                                             b1i, b1h, b2i, b2h, b3i, b3h,
                                             fc1w, fc1b, y);
        k_fc2<<<Bc / 8, 256, 0, stream>>>(y, fc2w, fc2b,
                                          out + (size_t)c * Bc * 21);
    }
}

// Round 7
// 596.769 us; speedup vs baseline: 1.5566x; 1.5566x over previous
//
#include <hip/hip_runtime.h>
#include <hip/hip_bf16.h>
#include <stdint.h>

// ---------------------------------------------------------------------------
// LSTM2: 3 stacked single-step LSTM cells (h0=c0=0 => f-gate dead) + fc1+fc2.
// B=8192, I=128, T=21 -> M = 172032 rows. ALL I/O f32; internals bf16 MFMA.
// R6: R3 pipeline skeleton + register-resident W (grid-stride over row tiles),
// XOR-swizzled A staging (conflict-free), single-barrier ping-pong A DMA.
// ---------------------------------------------------------------------------

typedef __attribute__((ext_vector_type(8))) short bf16x8;
typedef __attribute__((ext_vector_type(4))) float f32x4;

#define M_ROWS 172032
#define BATCH  8192

__device__ __forceinline__ float bf2f(unsigned short u) {
    union { unsigned int i; float f; } v; v.i = ((unsigned int)u) << 16; return v.f;
}
__device__ __forceinline__ unsigned short f2bf(float f) {
    union { float f; unsigned int i; } v; v.f = f;
    unsigned int r = v.i + 0x7fffu + ((v.i >> 16) & 1u);
    return (unsigned short)(r >> 16);
}
__device__ __forceinline__ float sigmoidf_(float x) {
    return __builtin_amdgcn_rcpf(1.0f + __expf(-x));   // inf-safe
}
__device__ __forceinline__ float tanhf_(float x) {
    x = fminf(fmaxf(x, -20.0f), 20.0f);
    float e = __expf(-2.0f * x);
    return (1.0f - e) * __builtin_amdgcn_rcpf(1.0f + e);
}
// async global->LDS DMA: 16B/lane, dest = wave-uniform base + lane*16
__device__ __forceinline__ void g2l16(const unsigned short* g, unsigned short* l) {
    __builtin_amdgcn_global_load_lds(
        (const __attribute__((address_space(1))) unsigned int*)g,
        (__attribute__((address_space(3))) unsigned int*)l, 16, 0, 0);
}

// ---------------------------------------------------------------------------
__global__ __launch_bounds__(256) void k_convert(
    const float* __restrict__ src, unsigned short* __restrict__ dst, int n4)
{
    int i = blockIdx.x * 256 + threadIdx.x;
    if (i < n4) {
        float4 v = ((const float4*)src)[i];
        ushort4 o;
        o.x = f2bf(v.x); o.y = f2bf(v.y); o.z = f2bf(v.z); o.w = f2bf(v.w);
        ((ushort4*)dst)[i] = o;
    }
}

// ---------------------------------------------------------------------------
// x (Bc, 128, 21) f32 -> xt (Bc*21, 128) bf16 row-major. One block per b.
// ---------------------------------------------------------------------------
__global__ __launch_bounds__(256) void k_transpose(
    const float* __restrict__ x, unsigned short* __restrict__ xt)
{
    __shared__ unsigned short tile[128 * 22];
    const int b = blockIdx.x, tid = threadIdx.x;
    const float* xb = x + (size_t)b * 2688;
    for (int idx = tid; idx < 2688; idx += 256) {
        int i = idx / 21, t = idx - i * 21;
        tile[i * 22 + t] = f2bf(xb[idx]);
    }
    __syncthreads();
    unsigned short* xtb = xt + (size_t)b * 2688;
    for (int idx = tid; idx < 2688; idx += 256) {
        int t = idx >> 7, i = idx & 127;
        xtb[t * 128 + i] = tile[i * 22 + t];
    }
}

// ---------------------------------------------------------------------------
// GEMM + LSTM activation, W register-resident, grid-stride over row tiles.
// A: (R,K) bf16. W: (4*HG,K) bf16, gates i,f,g,o (f skipped, c0=0).
// Grid: (HG/64 col groups, NB). Block: 256 thr, 4 waves (2 row x 2 col);
// block tile 128r x 64c x 3 gates; wave tile 64r x 32c, m=4 n=2 frags.
// ---------------------------------------------------------------------------
template<int K, int HG>
__global__ __launch_bounds__(256, 2) void k_gemm_reg(
    const unsigned short* __restrict__ A,
    const unsigned short* __restrict__ W,
    const float* __restrict__ bih,
    const float* __restrict__ bhh,
    unsigned short* __restrict__ Hout,
    int ntiles)
{
    constexpr int NC = K / 64;                 // 64-k chunks per tile
    __shared__ __align__(16) unsigned short sbuf[2 * 128 * 64];  // 32 KB

    const int tid  = threadIdx.x;
    const int wave = tid >> 6;
    const int lane = tid & 63;
    const int wm = wave >> 1;    // 0..1 row wave
    const int wn = wave & 1;     // 0..1 col wave
    const int quad = lane >> 4;
    const int rsel = lane & 15;
    const int r7   = rsel & 7;
    const int c0 = blockIdx.x * 64;

    const int l_hi = lane >> 3;                 // 0..7: row within 8-row group
    const int l_lo = (lane & 7) * 8;            // k granule (W stage, unswizzled)
    const int swl  = ((lane & 7) ^ l_hi) * 8;   // A stage: swizzled source granule

    // ---- biases (per wave, once) ----
    float bias[3][2];
#pragma unroll
    for (int g = 0; g < 3; ++g) {
        int gb = (g == 0) ? 0 : (g + 1) * HG;   // i->0, g->2HG, o->3HG
#pragma unroll
        for (int n = 0; n < 2; ++n) {
            int col = gb + c0 + wn * 32 + n * 16 + rsel;
            bias[g][n] = bih[col] + bhh[col];
        }
    }

    // ---- W preload into registers (staged via LDS, coalesced DMA) ----
    bf16x8 wreg[2 * NC][3][2];
#pragma unroll
    for (int kc = 0; kc < NC; ++kc) {
        const int kk = kc * 64;
        // stage 192 rows x 64 k (R3's proven 6-DMA pattern)
#pragma unroll
        for (int i = 0; i < 6; ++i) {
            int row  = wave * 48 + i * 8;
            int lrow = row + l_hi;
            int gate = lrow >> 6;
            int n    = lrow & 63;
            int gbase = (gate == 0) ? 0 : (gate + 1) * HG;
            g2l16(W + (size_t)(gbase + c0 + n) * K + kk + l_lo, &sbuf[row * 64]);
        }
        __syncthreads();
#pragma unroll
        for (int ks2 = 0; ks2 < 2; ++ks2) {
            const int koff = ks2 * 32 + quad * 8;
#pragma unroll
            for (int g = 0; g < 3; ++g)
#pragma unroll
                for (int n = 0; n < 2; ++n)
                    wreg[kc * 2 + ks2][g][n] = *(const bf16x8*)
                        &sbuf[(g * 64 + wn * 32 + n * 16 + rsel) * 64 + koff];
        }
        __syncthreads();
    }

    // ---- grid-stride over 128-row tiles ----
    for (int t = blockIdx.y; t < ntiles; t += gridDim.y) {
        const size_t r0 = (size_t)t * 128;

        // DMA chunk 0 -> buf 0 (swizzled source granule)
#pragma unroll
        for (int i = 0; i < 4; ++i) {
            int row = wave * 32 + i * 8;
            g2l16(A + (r0 + row + l_hi) * K + 0 + swl, &sbuf[row * 64]);
        }
        __syncthreads();

        f32x4 acc[3][4][2];
#pragma unroll
        for (int g = 0; g < 3; ++g)
#pragma unroll
            for (int m = 0; m < 4; ++m)
#pragma unroll
                for (int n = 0; n < 2; ++n)
                    acc[g][m][n] = (f32x4){0.f, 0.f, 0.f, 0.f};

#pragma unroll
        for (int c = 0; c < NC; ++c) {
            // prefetch next chunk into the other buffer (overlaps compute)
            if (c + 1 < NC) {
                unsigned short* nb = sbuf + ((c + 1) & 1) * (128 * 64);
#pragma unroll
                for (int i = 0; i < 4; ++i) {
                    int row = wave * 32 + i * 8;
                    g2l16(A + (r0 + row + l_hi) * K + (c + 1) * 64 + swl, &nb[row * 64]);
                }
            }
            const unsigned short* cb = sbuf + (c & 1) * (128 * 64);
#pragma unroll
            for (int ks2 = 0; ks2 < 2; ++ks2) {
                bf16x8 af[4];
                const int pg = ((ks2 * 4 + quad) ^ r7) * 8;
#pragma unroll
                for (int m = 0; m < 4; ++m)
                    af[m] = *(const bf16x8*)&cb[(wm * 64 + m * 16 + rsel) * 64 + pg];
#pragma unroll
                for (int g = 0; g < 3; ++g)
#pragma unroll
                    for (int m = 0; m < 4; ++m)
#pragma unroll
                        for (int n = 0; n < 2; ++n)
                            acc[g][m][n] = __builtin_amdgcn_mfma_f32_16x16x32_bf16(
                                af[m], wreg[c * 2 + ks2][g][n], acc[g][m][n], 0, 0, 0);
            }
            __syncthreads();   // DMA c+1 landed; buf (c&1) free for c+2
        }

        // ---- epilogue: C/D layout col = rsel, row = quad*4 + reg ----
#pragma unroll
        for (int m = 0; m < 4; ++m)
#pragma unroll
            for (int n = 0; n < 2; ++n) {
                f32x4 vi = acc[0][m][n], vg = acc[1][m][n], vo = acc[2][m][n];
                int col = c0 + wn * 32 + n * 16 + rsel;
#pragma unroll
                for (int r = 0; r < 4; ++r) {
                    size_t row = r0 + wm * 64 + m * 16 + quad * 4 + r;
                    float cv = sigmoidf_(vi[r] + bias[0][n]) * tanhf_(vg[r] + bias[1][n]);
                    float h  = sigmoidf_(vo[r] + bias[2][n]) * tanhf_(cv);
                    Hout[row * HG + col] = f2bf(h);
                }
            }
    }
}

// ---------------------------------------------------------------------------
// fc1 + fc2 fused: y[b,t] = h3[b,t,:]@fc1_w + fc1_b ; out = y@fc2_w^T + fc2_b
// h3 bf16; fc weights/biases f32; out f32. 8 batches per block. (R3 proven)
// ---------------------------------------------------------------------------
#define FSTR 169
__global__ __launch_bounds__(256) void k_final(
    const unsigned short* __restrict__ h3,
    const float* __restrict__ fc1w,
    const float* __restrict__ fc1b,
    const float* __restrict__ fc2w,
    const float* __restrict__ fc2b,
    float* __restrict__ out)
{
    __shared__ unsigned short ht[128 * FSTR];
    __shared__ float fwl[128];
    __shared__ float yl[168];
    __shared__ float f2l[441];
    __shared__ float f2bl[21];

    const int tid = threadIdx.x;
    const int b0 = blockIdx.x * 8;

    if (tid < 128) fwl[tid] = fc1w[tid];
    for (int i = tid; i < 441; i += 256) f2l[i] = fc2w[i];
    if (tid < 21) f2bl[tid] = fc2b[tid];

    const unsigned int* hsrc = (const unsigned int*)(h3 + (size_t)b0 * 2688);
    for (int gi = tid; gi < 10752; gi += 256) {
        unsigned int v = hsrc[gi];
        int e = gi * 2;
        int task = e >> 7;
        int c = e & 127;
        ht[c * FSTR + task] = (unsigned short)(v & 0xffffu);
        ht[(c + 1) * FSTR + task] = (unsigned short)(v >> 16);
    }
    __syncthreads();

    const float f1b = fc1b[0];
    if (tid < 168) {
        float s = f1b;
#pragma unroll 8
        for (int c = 0; c < 128; ++c)
            s += fwl[c] * bf2f(ht[c * FSTR + tid]);
        yl[tid] = s;
    }
    __syncthreads();
    if (tid < 168) {
        int bloc = tid / 21;
        int tp = tid - bloc * 21;
        float s = f2bl[tp];
#pragma unroll
        for (int t = 0; t < 21; ++t)
            s += yl[bloc * 21 + t] * f2l[tp * 21 + t];
        out[(size_t)(b0 + bloc) * 21 + tp] = s;
    }
}

// ---------------------------------------------------------------------------
extern "C" void kernel_launch(void* const* d_in, const int* in_sizes, int n_in,
                              void* d_out, int out_size, void* d_ws, size_t ws_size,
                              hipStream_t stream)
{
    const float* x    = (const float*)d_in[0];
    const float* W1   = (const float*)d_in[1];
    const float* b1i  = (const float*)d_in[2];
    const float* b1h  = (const float*)d_in[3];
    const float* W2   = (const float*)d_in[4];
    const float* b2i  = (const float*)d_in[5];
    const float* b2h  = (const float*)d_in[6];
    const float* W3   = (const float*)d_in[7];
    const float* b3i  = (const float*)d_in[8];
    const float* b3h  = (const float*)d_in[9];
    const float* fc1w = (const float*)d_in[10];
    const float* fc1b = (const float*)d_in[11];
    const float* fc2w = (const float*)d_in[12];
    const float* fc2b = (const float*)d_in[13];
    float* out = (float*)d_out;

    // ws: [Wc1 1024x128][Wc2 1024x256][Wc3 512x256] bf16 (1 MB), then
    // per-chunk: xt(R*128) h1(R*256) h2(R*256) h3(R*128) bf16 = 1536 B/row.
    unsigned short* Wc1 = (unsigned short*)d_ws;
    unsigned short* Wc2 = Wc1 + 131072;
    unsigned short* Wc3 = Wc2 + 262144;
    unsigned short* buf = Wc3 + 131072;

    int C = 1;
    while (C < 64 && 1048576 + (size_t)(M_ROWS / C) * 1536 > ws_size) C <<= 1;
    const int R  = M_ROWS / C;   // multiple of 2688 (21*128)
    const int Bc = BATCH / C;
    const int NT = R / 128;                      // row tiles
    const int NB = (NT < 336) ? NT : 336;        // grid-stride span

    unsigned short* xt = buf;
    unsigned short* h1 = xt + (size_t)R * 128;
    unsigned short* h2 = h1 + (size_t)R * 256;
    unsigned short* h3 = h2 + (size_t)R * 256;

    k_convert<<<128, 256, 0, stream>>>(W1, Wc1, 32768);
    k_convert<<<256, 256, 0, stream>>>(W2, Wc2, 65536);
    k_convert<<<128, 256, 0, stream>>>(W3, Wc3, 32768);

    for (int c = 0; c < C; ++c) {
        const float* xc = x + (size_t)c * Bc * 2688;
        k_transpose<<<Bc, 256, 0, stream>>>(xc, xt);
        k_gemm_reg<128, 256><<<dim3(4, NB), 256, 0, stream>>>(xt, Wc1, b1i, b1h, h1, NT);
        k_gemm_reg<256, 256><<<dim3(4, NB), 256, 0, stream>>>(h1, Wc2, b2i, b2h, h2, NT);
        k_gemm_reg<256, 128><<<dim3(2, NB), 256, 0, stream>>>(h2, Wc3, b3i, b3h, h3, NT);
        k_final<<<Bc / 8, 256, 0, stream>>>(h3, fc1w, fc1b, fc2w, fc2b,
                                            out + (size_t)c * Bc * 21);
    }
}

// Round 8
// 444.505 us; speedup vs baseline: 2.0898x; 1.3425x over previous
//
#include <hip/hip_runtime.h>
#include <hip/hip_bf16.h>
#include <stdint.h>

// ---------------------------------------------------------------------------
// LSTM2: 3 stacked single-step LSTM cells (h0=c0=0 => f-gate dead) + fc1+fc2.
// B=8192, I=128, T=21 -> M = 172032 rows. ALL I/O f32; internals bf16 MFMA.
// R8 = R4 structure + XOR-swizzled LDS tiles (conflict-free frag reads)
//    + 3 blocks/CU occupancy.
// ---------------------------------------------------------------------------

typedef __attribute__((ext_vector_type(8))) short bf16x8;
typedef __attribute__((ext_vector_type(4))) float f32x4;

#define M_ROWS 172032
#define BATCH  8192

__device__ __forceinline__ float bf2f(unsigned short u) {
    union { unsigned int i; float f; } v; v.i = ((unsigned int)u) << 16; return v.f;
}
__device__ __forceinline__ unsigned short f2bf(float f) {
    union { float f; unsigned int i; } v; v.f = f;
    unsigned int r = v.i + 0x7fffu + ((v.i >> 16) & 1u);
    return (unsigned short)(r >> 16);
}
__device__ __forceinline__ float sigmoidf_(float x) {
    return __builtin_amdgcn_rcpf(1.0f + __expf(-x));   // inf-safe
}
__device__ __forceinline__ float tanhf_(float x) {
    x = fminf(fmaxf(x, -20.0f), 20.0f);
    float e = __expf(-2.0f * x);
    return (1.0f - e) * __builtin_amdgcn_rcpf(1.0f + e);
}
// async global->LDS DMA: 16B/lane, dest = wave-uniform base + lane*16
__device__ __forceinline__ void g2l16(const unsigned short* g, unsigned short* l) {
    __builtin_amdgcn_global_load_lds(
        (const __attribute__((address_space(1))) unsigned int*)g,
        (__attribute__((address_space(3))) unsigned int*)l, 16, 0, 0);
}

// ---------------------------------------------------------------------------
__global__ __launch_bounds__(256) void k_convert(
    const float* __restrict__ src, unsigned short* __restrict__ dst, int n4)
{
    int i = blockIdx.x * 256 + threadIdx.x;
    if (i < n4) {
        float4 v = ((const float4*)src)[i];
        ushort4 o;
        o.x = f2bf(v.x); o.y = f2bf(v.y); o.z = f2bf(v.z); o.w = f2bf(v.w);
        ((ushort4*)dst)[i] = o;
    }
}

// ---------------------------------------------------------------------------
// x (Bc, 128, 21) f32 -> xt (Bc*21, 128) bf16 row-major. One block per b.
// ---------------------------------------------------------------------------
__global__ __launch_bounds__(256) void k_transpose(
    const float* __restrict__ x, unsigned short* __restrict__ xt)
{
    __shared__ unsigned short tile[128 * 22];
    const int b = blockIdx.x, tid = threadIdx.x;
    const float* xb = x + (size_t)b * 2688;
    for (int idx = tid; idx < 2688; idx += 256) {
        int i = idx / 21, t = idx - i * 21;
        tile[i * 22 + t] = f2bf(xb[idx]);
    }
    __syncthreads();
    unsigned short* xtb = xt + (size_t)b * 2688;
    for (int idx = tid; idx < 2688; idx += 256) {
        int t = idx >> 7, i = idx & 127;
        xtb[t * 128 + i] = tile[i * 22 + t];
    }
}

// ---------------------------------------------------------------------------
// h = sigmoid(o) * tanh( sigmoid(i) * tanh(g) ),  gates = A @ W^T + (bih+bhh)
// A: (R,K) bf16. W: (4*HG,K) bf16, gates i,f,g,o (f skipped, c0=0).
// Grid: (HG/64 col groups, R/128 row bands). Block 256 thr = 4 waves (2x2);
// wave tile 64r x 32c x 3 gates (m=4, n=2 MFMA 16x16x32 frags).
// LDS tiles XOR-granule-swizzled: phys_granule = logical ^ (row & 7)
// => all frag reads are <=2-way bank aliased (free). DMA source applies the
// same (self-inverse) swizzle: src granule = (lane&7) ^ (lane>>3).
// ---------------------------------------------------------------------------
template<int K, int HG>
__global__ __launch_bounds__(256, 3) void k_gemm_act(
    const unsigned short* __restrict__ A,
    const unsigned short* __restrict__ W,
    const float* __restrict__ bih,
    const float* __restrict__ bhh,
    unsigned short* __restrict__ Hout)
{
    __shared__ __align__(16) unsigned short As[128 * 64];  // [row][k] swizzled
    __shared__ __align__(16) unsigned short Ws[192 * 64];  // [gate*64+n][k] swizzled
    __shared__ float Bs[192];

    const int tid  = threadIdx.x;
    const int wave = tid >> 6;
    const int lane = tid & 63;
    const int wm = wave >> 1;    // 0..1 -> 64-row band
    const int wn = wave & 1;     // 0..1 -> 32-col slice
    const int quad = lane >> 4;
    const int rsel = lane & 15;
    const int r7   = rsel & 7;
    const int c0 = blockIdx.x * 64;
    const int r0 = blockIdx.y * 128;

    if (tid < 192) {
        int g = tid >> 6, c = tid & 63;
        int gbase = (g == 0) ? 0 : (g + 1) * HG;   // i->0, g->2HG, o->3HG
        int idx = gbase + c0 + c;
        Bs[tid] = bih[idx] + bhh[idx];
    }

    f32x4 acc[3][4][2];
#pragma unroll
    for (int g = 0; g < 3; ++g)
#pragma unroll
        for (int m = 0; m < 4; ++m)
#pragma unroll
            for (int n = 0; n < 2; ++n)
                acc[g][m][n] = (f32x4){0.f, 0.f, 0.f, 0.f};

    const int l_hi = lane >> 3;                  // row within 8-row DMA group
    const int swl  = ((lane & 7) ^ l_hi) * 8;    // swizzled source granule

#pragma unroll
    for (int kk = 0; kk < K; kk += 64) {
        if (kk) __syncthreads();       // prev tile fully consumed
        // stage A tile: 128 rows x 64 k (4 DMA/wave, 8 rows each)
#pragma unroll
        for (int i = 0; i < 4; ++i) {
            int row = wave * 32 + i * 8;
            g2l16(A + (size_t)(r0 + row + l_hi) * K + kk + swl, &As[row * 64]);
        }
        // stage W tiles: 3 gates x 64 cols x 64 k (6 DMA/wave)
#pragma unroll
        for (int i = 0; i < 6; ++i) {
            int row  = wave * 48 + i * 8;      // 0..191 combined gate space
            int lrow = row + l_hi;
            int gate = lrow >> 6;
            int n    = lrow & 63;
            int gbase = (gate == 0) ? 0 : (gate + 1) * HG;
            g2l16(W + (size_t)(gbase + c0 + n) * K + kk + swl, &Ws[row * 64]);
        }
        __syncthreads();               // DMA landed

        // ---- MFMA on the staged 64-k tile ----
#pragma unroll
        for (int ks2 = 0; ks2 < 2; ++ks2) {
            const int pg = ((ks2 * 4 + quad) ^ r7) * 8;   // swizzled granule
            bf16x8 af[4];
#pragma unroll
            for (int m = 0; m < 4; ++m)
                af[m] = *(const bf16x8*)&As[(wm * 64 + m * 16 + rsel) * 64 + pg];
            bf16x8 bfr[3][2];
#pragma unroll
            for (int g = 0; g < 3; ++g)
#pragma unroll
                for (int n = 0; n < 2; ++n)
                    bfr[g][n] = *(const bf16x8*)&Ws[(g * 64 + wn * 32 + n * 16 + rsel) * 64 + pg];
#pragma unroll
            for (int g = 0; g < 3; ++g)
#pragma unroll
                for (int m = 0; m < 4; ++m)
#pragma unroll
                    for (int n = 0; n < 2; ++n)
                        acc[g][m][n] = __builtin_amdgcn_mfma_f32_16x16x32_bf16(
                            af[m], bfr[g][n], acc[g][m][n], 0, 0, 0);
        }
    }

    // epilogue: C/D layout col = lane&15, row = (lane>>4)*4 + reg
#pragma unroll
    for (int m = 0; m < 4; ++m) {
#pragma unroll
        for (int n = 0; n < 2; ++n) {
            int cloc = wn * 32 + n * 16 + rsel;
            float bi = Bs[cloc], bg = Bs[64 + cloc], bo = Bs[128 + cloc];
            f32x4 vi = acc[0][m][n], vg = acc[1][m][n], vo = acc[2][m][n];
#pragma unroll
            for (int r = 0; r < 4; ++r) {
                int row = r0 + wm * 64 + m * 16 + quad * 4 + r;
                float cv = sigmoidf_(vi[r] + bi) * tanhf_(vg[r] + bg);
                float h  = sigmoidf_(vo[r] + bo) * tanhf_(cv);
                Hout[(size_t)row * HG + c0 + cloc] = f2bf(h);
            }
        }
    }
}

// ---------------------------------------------------------------------------
// fc1 + fc2 fused: y[b,t] = h3[b,t,:]@fc1_w + fc1_b ; out = y@fc2_w^T + fc2_b
// h3 bf16; fc weights/biases f32; out f32. 8 batches per block.
// ---------------------------------------------------------------------------
#define FSTR 169
__global__ __launch_bounds__(256) void k_final(
    const unsigned short* __restrict__ h3,
    const float* __restrict__ fc1w,
    const float* __restrict__ fc1b,
    const float* __restrict__ fc2w,
    const float* __restrict__ fc2b,
    float* __restrict__ out)
{
    __shared__ unsigned short ht[128 * FSTR];
    __shared__ float fwl[128];
    __shared__ float yl[168];
    __shared__ float f2l[441];
    __shared__ float f2bl[21];

    const int tid = threadIdx.x;
    const int b0 = blockIdx.x * 8;

    if (tid < 128) fwl[tid] = fc1w[tid];
    for (int i = tid; i < 441; i += 256) f2l[i] = fc2w[i];
    if (tid < 21) f2bl[tid] = fc2b[tid];

    const unsigned int* hsrc = (const unsigned int*)(h3 + (size_t)b0 * 2688);
    for (int gi = tid; gi < 10752; gi += 256) {
        unsigned int v = hsrc[gi];
        int e = gi * 2;
        int task = e >> 7;
        int c = e & 127;
        ht[c * FSTR + task] = (unsigned short)(v & 0xffffu);
        ht[(c + 1) * FSTR + task] = (unsigned short)(v >> 16);
    }
    __syncthreads();

    const float f1b = fc1b[0];
    if (tid < 168) {
        float s = f1b;
#pragma unroll 8
        for (int c = 0; c < 128; ++c)
            s += fwl[c] * bf2f(ht[c * FSTR + tid]);
        yl[tid] = s;
    }
    __syncthreads();
    if (tid < 168) {
        int bloc = tid / 21;
        int tp = tid - bloc * 21;
        float s = f2bl[tp];
#pragma unroll
        for (int t = 0; t < 21; ++t)
            s += yl[bloc * 21 + t] * f2l[tp * 21 + t];
        out[(size_t)(b0 + bloc) * 21 + tp] = s;
    }
}

// ---------------------------------------------------------------------------
extern "C" void kernel_launch(void* const* d_in, const int* in_sizes, int n_in,
                              void* d_out, int out_size, void* d_ws, size_t ws_size,
                              hipStream_t stream)
{
    const float* x    = (const float*)d_in[0];
    const float* W1   = (const float*)d_in[1];
    const float* b1i  = (const float*)d_in[2];
    const float* b1h  = (const float*)d_in[3];
    const float* W2   = (const float*)d_in[4];
    const float* b2i  = (const float*)d_in[5];
    const float* b2h  = (const float*)d_in[6];
    const float* W3   = (const float*)d_in[7];
    const float* b3i  = (const float*)d_in[8];
    const float* b3h  = (const float*)d_in[9];
    const float* fc1w = (const float*)d_in[10];
    const float* fc1b = (const float*)d_in[11];
    const float* fc2w = (const float*)d_in[12];
    const float* fc2b = (const float*)d_in[13];
    float* out = (float*)d_out;

    // ws: [Wc1 1024x128][Wc2 1024x256][Wc3 512x256] bf16 (1 MB), then
    // per-chunk: xt(R*128) h1(R*256) h2(R*256) h3(R*128) bf16 = 1536 B/row.
    unsigned short* Wc1 = (unsigned short*)d_ws;
    unsigned short* Wc2 = Wc1 + 131072;
    unsigned short* Wc3 = Wc2 + 262144;
    unsigned short* buf = Wc3 + 131072;

    int C = 1;
    while (C < 64 && 1048576 + (size_t)(M_ROWS / C) * 1536 > ws_size) C <<= 1;
    const int R  = M_ROWS / C;   // multiple of 2688 (21*128)
    const int Bc = BATCH / C;

    unsigned short* xt = buf;
    unsigned short* h1 = xt + (size_t)R * 128;
    unsigned short* h2 = h1 + (size_t)R * 256;
    unsigned short* h3 = h2 + (size_t)R * 256;

    k_convert<<<128, 256, 0, stream>>>(W1, Wc1, 32768);
    k_convert<<<256, 256, 0, stream>>>(W2, Wc2, 65536);
    k_convert<<<128, 256, 0, stream>>>(W3, Wc3, 32768);

    for (int c = 0; c < C; ++c) {
        const float* xc = x + (size_t)c * Bc * 2688;
        k_transpose<<<Bc, 256, 0, stream>>>(xc, xt);
        k_gemm_act<128, 256><<<dim3(4, R / 128), 256, 0, stream>>>(xt, Wc1, b1i, b1h, h1);
        k_gemm_act<256, 256><<<dim3(4, R / 128), 256, 0, stream>>>(h1, Wc2, b2i, b2h, h2);
        k_gemm_act<256, 128><<<dim3(2, R / 128), 256, 0, stream>>>(h2, Wc3, b3i, b3h, h3);
        k_final<<<Bc / 8, 256, 0, stream>>>(h3, fc1w, fc1b, fc2w, fc2b,
                                            out + (size_t)c * Bc * 21);
    }
}